// Round 4
// baseline (304.456 us; speedup 1.0000x reference)
//
#include <hip/hip_runtime.h>
#include <cmath>

// GPTNeoXRoutedMLP: N=2048 tokens, H=1024, F=4096, E=8, topk=2.
// R4: register-tile transpose (no LDS, no barriers, 64B/lane writes) for weight
// f32->bf16 transposition; w1t in prep (|| x-cvt || router), w2t as gemm1 tail.
// GEMMs: 2-phase double-buffered, global_load_lds(16B), XOR-swizzled LDS.

#define H_DIM 1024
#define F_DIM 4096
#define E_NUM 8
#define N_TOK 2048
#define BK 64
#define MAX_SLOTS 5120
#define MAX_MT (MAX_SLOTS / 128)   // 40 row tiles
#define G1_GRID (MAX_MT * 32)      // 1280
#define G2_GRID (MAX_MT * 16)      // 640
#define TCVT_BLKS 4096             // per weight tensor (32M elems / 8192 per block)

typedef short s16x8 __attribute__((ext_vector_type(8)));
typedef float f32x4 __attribute__((ext_vector_type(4)));

__device__ __forceinline__ unsigned short f2bf(float f) {
  unsigned int u = __float_as_uint(f);
  u += 0x7fffu + ((u >> 16) & 1u);   // RNE
  return (unsigned short)(u >> 16);
}

__device__ __forceinline__ void gload_lds16(const void* g, void* l) {
  __builtin_amdgcn_global_load_lds(
      (const __attribute__((address_space(1))) unsigned int*)g,
      (__attribute__((address_space(3))) unsigned int*)l, 16, 0, 0);
}

__device__ __forceinline__ int xcd_swz(int orig, int nwg) {
  const int cpx = nwg >> 3;   // nwg multiple of 8 (1280 / 640)
  return (orig & 7) * cpx + (orig >> 3);
}

__device__ __forceinline__ float fast_gelu(float v) {
  // tanh-form GELU; |err vs erf-GELU| < 4e-4 (budget 3.8e-2)
  const float w = v * (1.0f + 0.044715f * v * v);
  const float t = __expf(-1.5957691216f * w);
  return v / (1.0f + t);
}

// Register-tile transpose-convert: in [E][R][C] f32 -> out [E][C][R] bf16.
// Block covers 32 rows x 256 cols; thread owns 1 col x 32 rows.
// Loads: lanes span consecutive cols -> 256B coalesced per row step.
// Stores: 4x16B contiguous = 64B full line per lane.
__device__ __forceinline__ void fast_tcvt(const float* __restrict__ in,
                                          unsigned short* __restrict__ out,
                                          int R, int C, int tile) {
  const int ct = C >> 8;
  const int nb = (R >> 5) * ct;
  const int e = tile / nb;
  const int rem = tile - e * nb;
  const int r0 = (rem / ct) << 5;
  const int c0 = (rem % ct) << 8;
  const size_t eb = (size_t)e * R * C;
  const int c = c0 + threadIdx.x;
  const float* ip = in + eb + (size_t)r0 * C + c;
  unsigned short* op = out + eb + (size_t)c * R + r0;
  float v[32];
#pragma unroll
  for (int j = 0; j < 32; ++j) v[j] = ip[(size_t)j * C];
#pragma unroll
  for (int q = 0; q < 4; ++q) {
    s16x8 u;
#pragma unroll
    for (int j = 0; j < 8; ++j) u[j] = (short)f2bf(v[q * 8 + j]);
    *(s16x8*)(op + q * 8) = u;
  }
}

// ---------------- prep1: w1t (4096 blk) | x cvt (1024 blk) | router (512 blk) ----------------
__global__ __launch_bounds__(256) void prep1_k(
    const float* __restrict__ w1, unsigned short* __restrict__ wt1,
    const float* __restrict__ x, unsigned short* __restrict__ xb,
    const float* __restrict__ rw, int* __restrict__ meta,
    int* __restrict__ topk_e, float* __restrict__ topk_s) {
  const int b = blockIdx.x;
  const int t = threadIdx.x;
  if (b < TCVT_BLKS) {  // w1 [E][H][F] -> wt1 [E][F][H]
    fast_tcvt(w1, wt1, H_DIM, F_DIM, b);
    return;
  }
  if (b < TCVT_BLKS + 1024) {  // x f32 -> bf16
    const size_t i = (((size_t)(b - TCVT_BLKS)) * 256 + t) * 8;
    f32x4 a = *(const f32x4*)(x + i);
    f32x4 c = *(const f32x4*)(x + i + 4);
    s16x8 u;
#pragma unroll
    for (int j = 0; j < 4; ++j) { u[j] = (short)f2bf(a[j]); u[4 + j] = (short)f2bf(c[j]); }
    *(s16x8*)&xb[i] = u;
    return;
  }
  // router: one token per wave
  const int n = (b - TCVT_BLKS - 1024) * 4 + (t >> 6);
  const int l = t & 63;
  float part[E_NUM];
#pragma unroll
  for (int e = 0; e < E_NUM; ++e) part[e] = 0.f;
  const float* xr = x + (size_t)n * H_DIM;
  for (int h = l; h < H_DIM; h += 64) {
    const float xv = xr[h];
    const float* rwr = rw + h * E_NUM;
#pragma unroll
    for (int e = 0; e < E_NUM; ++e) part[e] += xv * rwr[e];
  }
#pragma unroll
  for (int e = 0; e < E_NUM; ++e) {
#pragma unroll
    for (int off = 32; off > 0; off >>= 1) part[e] += __shfl_down(part[e], off);
  }
  if (l == 0) {
    float v0 = -3.4e38f, v1 = -3.4e38f;
    int i0 = 0, i1 = 0;
#pragma unroll
    for (int e = 0; e < E_NUM; ++e) {
      float v = part[e];
      if (v > v0) { v1 = v0; i1 = i0; v0 = v; i0 = e; }   // strict > : lowest index wins ties
      else if (v > v1) { v1 = v; i1 = e; }
    }
    const float e1 = expf(v1 - v0);
    const float inv = 1.f / (1.f + e1);
    topk_e[2 * n] = i0; topk_e[2 * n + 1] = i1;
    topk_s[2 * n] = inv; topk_s[2 * n + 1] = e1 * inv;
    atomicAdd(&meta[i0], 1);
    atomicAdd(&meta[i1], 1);
  }
}

// ---------------- Scatter (slot_token pre-init to -1 via memset 0xFF) ----------------
__global__ __launch_bounds__(256) void scatter_k(
    int* __restrict__ meta, const int* __restrict__ topk_e,
    const float* __restrict__ topk_s, int* __restrict__ slot_token,
    float* __restrict__ slot_score) {
  __shared__ int soff[9];
  __shared__ int scur[8];
  const int t = threadIdx.x;
  if (t == 0) {
    int acc = 0;
    for (int e = 0; e < E_NUM; ++e) {
      soff[e] = acc;
      meta[8 + e] = acc;
      acc += ((meta[e] + 127) / 128) * 128;
    }
    soff[8] = acc;
    meta[16] = acc;
  }
  if (t < 8) scur[t] = 0;
  __syncthreads();
  for (int a = t; a < N_TOK * 2; a += 256) {
    const int e = topk_e[a];
    const int pos = atomicAdd(&scur[e], 1);
    const int slot = soff[e] + pos;
    slot_token[slot] = a >> 1;
    slot_score[slot] = topk_s[a];
  }
}

// ============ GEMM1 (+ fused w2t tail): h = gelu(xb[gather] @ w1t^T + b1) ============
__global__ __launch_bounds__(256, 2) void gemm1_f(
    const unsigned short* __restrict__ xb, const unsigned short* __restrict__ w1t,
    const float* __restrict__ b1, const int* __restrict__ meta,
    const int* __restrict__ slot_token, unsigned short* __restrict__ hbuf,
    const float* __restrict__ w2, unsigned short* __restrict__ wt2) {
  __shared__ __align__(16) char lraw[65536];
  if (blockIdx.x >= G1_GRID) {   // fused tail: w2 [E][F][H] -> wt2 [E][H][F]
    fast_tcvt(w2, wt2, F_DIM, H_DIM, blockIdx.x - G1_GRID);
    return;
  }
  unsigned short* Al = (unsigned short*)lraw;              // [2][128*64]
  unsigned short* Bl = (unsigned short*)(lraw + 32768);    // [2][128*64]
  const int total = meta[16];
  const int wgid = xcd_swz(blockIdx.x, G1_GRID);
  const int mt = wgid >> 5, nt = wgid & 31;
  const int m0 = mt * 128;
  if (m0 >= total) return;
  int exp = 0;
#pragma unroll
  for (int e = 1; e < E_NUM; ++e) if (m0 >= meta[8 + e]) exp = e;
  const int n0 = nt * 128;
  const int t = threadIdx.x, w = t >> 6, l = t & 63;
  const int wm = w >> 1, wn = w & 1, lr = l & 15, lg = l >> 4;
  const int sr = l >> 3, sc = l & 7;

  const unsigned short* srcA[4];
  const unsigned short* srcB[4];
#pragma unroll
  for (int i = 0; i < 4; ++i) {
    const int r = (w * 4 + i) * 8 + sr;
    const int cd = sc ^ sr;            // pre-swizzled source chunk (r&7 == sr)
    int tk = slot_token[m0 + r]; if (tk < 0) tk = 0;
    srcA[i] = xb + (size_t)tk * H_DIM + cd * 8;
    srcB[i] = w1t + ((size_t)exp * F_DIM + n0 + r) * H_DIM + cd * 8;
  }

  const f32x4 fzero = {0.f, 0.f, 0.f, 0.f};
  f32x4 acc[4][4];
#pragma unroll
  for (int a = 0; a < 4; ++a)
#pragma unroll
    for (int b = 0; b < 4; ++b) acc[a][b] = fzero;

  // prologue: stage tile 0 into buf 0
#pragma unroll
  for (int i = 0; i < 4; ++i) {
    gload_lds16(srcA[i], Al + (w * 4 + i) * 512);
    gload_lds16(srcB[i], Bl + (w * 4 + i) * 512);
  }
  __syncthreads();
  int cur = 0;
  for (int kt = 0; kt < H_DIM / BK; ++kt) {
    const int nxt = cur ^ 1;
    if (kt + 1 < H_DIM / BK) {       // prefetch next tile while computing current
      const int k0 = (kt + 1) * BK;
#pragma unroll
      for (int i = 0; i < 4; ++i) {
        gload_lds16(srcA[i] + k0, Al + nxt * 8192 + (w * 4 + i) * 512);
        gload_lds16(srcB[i] + k0, Bl + nxt * 8192 + (w * 4 + i) * 512);
      }
    }
    const unsigned short* Ac = Al + cur * 8192;
    const unsigned short* Bc = Bl + cur * 8192;
#pragma unroll
    for (int kk = 0; kk < 2; ++kk) {
      s16x8 af[4], bb[4];
#pragma unroll
      for (int fm = 0; fm < 4; ++fm) {
        const int row = wm * 64 + fm * 16 + lr;
        af[fm] = *(const s16x8*)&Ac[row * 64 + (((kk * 4 + lg) ^ (lr & 7)) * 8)];
      }
#pragma unroll
      for (int fn = 0; fn < 4; ++fn) {
        const int row = wn * 64 + fn * 16 + lr;
        bb[fn] = *(const s16x8*)&Bc[row * 64 + (((kk * 4 + lg) ^ (lr & 7)) * 8)];
      }
#pragma unroll
      for (int fm = 0; fm < 4; ++fm)
#pragma unroll
        for (int fn = 0; fn < 4; ++fn)
          acc[fm][fn] = __builtin_amdgcn_mfma_f32_16x16x32_bf16(af[fm], bb[fn], acc[fm][fn], 0, 0, 0);
    }
    __syncthreads();
    cur = nxt;
  }
#pragma unroll
  for (int fn = 0; fn < 4; ++fn) {
    const int col = n0 + wn * 64 + fn * 16 + lr;
    const float bias = b1[exp * F_DIM + col];
#pragma unroll
    for (int fm = 0; fm < 4; ++fm) {
      const int rbase = m0 + wm * 64 + fm * 16 + lg * 4;
#pragma unroll
      for (int i = 0; i < 4; ++i) {
        hbuf[(size_t)(rbase + i) * F_DIM + col] = f2bf(fast_gelu(acc[fm][fn][i] + bias));
      }
    }
  }
}

// ============ GEMM2: out[token] += s*(hbuf @ w2t^T + b2), 128x64x64 dbuf ============
__global__ __launch_bounds__(256, 3) void gemm2_f(
    const unsigned short* __restrict__ hbuf, const unsigned short* __restrict__ w2t,
    const float* __restrict__ b2, const int* __restrict__ meta,
    const int* __restrict__ slot_token, const float* __restrict__ slot_score,
    float* __restrict__ out) {
  __shared__ __align__(16) char lraw[49152];
  unsigned short* Al = (unsigned short*)lraw;              // [2][128*64]
  unsigned short* Bl = (unsigned short*)(lraw + 32768);    // [2][64*64]
  const int total = meta[16];
  const int wgid = xcd_swz(blockIdx.x, G2_GRID);
  const int mt = wgid >> 4, nt = wgid & 15;
  const int m0 = mt * 128;
  if (m0 >= total) return;
  int exp = 0;
#pragma unroll
  for (int e = 1; e < E_NUM; ++e) if (m0 >= meta[8 + e]) exp = e;
  const int n0 = nt * 64;
  const int t = threadIdx.x, w = t >> 6, l = t & 63;
  const int wm = w >> 1, wn = w & 1, lr = l & 15, lg = l >> 4;
  const int sr = l >> 3, sc = l & 7;

  const unsigned short* srcA[4];
  const unsigned short* srcB[2];
#pragma unroll
  for (int i = 0; i < 4; ++i) {
    const int r = (w * 4 + i) * 8 + sr;
    srcA[i] = hbuf + (size_t)(m0 + r) * F_DIM + (sc ^ sr) * 8;
  }
#pragma unroll
  for (int i = 0; i < 2; ++i) {
    const int r = (w * 2 + i) * 8 + sr;
    srcB[i] = w2t + ((size_t)exp * H_DIM + n0 + r) * F_DIM + (sc ^ sr) * 8;
  }

  const f32x4 fzero = {0.f, 0.f, 0.f, 0.f};
  f32x4 acc[4][2];
#pragma unroll
  for (int a = 0; a < 4; ++a)
#pragma unroll
    for (int b = 0; b < 2; ++b) acc[a][b] = fzero;

  // prologue
#pragma unroll
  for (int i = 0; i < 4; ++i) gload_lds16(srcA[i], Al + (w * 4 + i) * 512);
#pragma unroll
  for (int i = 0; i < 2; ++i) gload_lds16(srcB[i], Bl + (w * 2 + i) * 512);
  __syncthreads();
  int cur = 0;
  for (int kt = 0; kt < F_DIM / BK; ++kt) {
    const int nxt = cur ^ 1;
    if (kt + 1 < F_DIM / BK) {
      const int k0 = (kt + 1) * BK;
#pragma unroll
      for (int i = 0; i < 4; ++i)
        gload_lds16(srcA[i] + k0, Al + nxt * 8192 + (w * 4 + i) * 512);
#pragma unroll
      for (int i = 0; i < 2; ++i)
        gload_lds16(srcB[i] + k0, Bl + nxt * 4096 + (w * 2 + i) * 512);
    }
    const unsigned short* Ac = Al + cur * 8192;
    const unsigned short* Bc = Bl + cur * 4096;
#pragma unroll
    for (int kk = 0; kk < 2; ++kk) {
      s16x8 af[4], bb[2];
#pragma unroll
      for (int fm = 0; fm < 4; ++fm) {
        const int row = wm * 64 + fm * 16 + lr;
        af[fm] = *(const s16x8*)&Ac[row * 64 + (((kk * 4 + lg) ^ (lr & 7)) * 8)];
      }
#pragma unroll
      for (int fn = 0; fn < 2; ++fn) {
        const int row = wn * 32 + fn * 16 + lr;
        bb[fn] = *(const s16x8*)&Bc[row * 64 + (((kk * 4 + lg) ^ (lr & 7)) * 8)];
      }
#pragma unroll
      for (int fm = 0; fm < 4; ++fm)
#pragma unroll
        for (int fn = 0; fn < 2; ++fn)
          acc[fm][fn] = __builtin_amdgcn_mfma_f32_16x16x32_bf16(af[fm], bb[fn], acc[fm][fn], 0, 0, 0);
    }
    __syncthreads();
    cur = nxt;
  }
#pragma unroll
  for (int fm = 0; fm < 4; ++fm) {
    const int rbase = m0 + wm * 64 + fm * 16 + lg * 4;
    int toks[4]; float ss[4];
#pragma unroll
    for (int i = 0; i < 4; ++i) {
      toks[i] = slot_token[rbase + i];
      ss[i] = slot_score[rbase + i];
    }
#pragma unroll
    for (int fn = 0; fn < 2; ++fn) {
      const int col = n0 + wn * 32 + fn * 16 + lr;
      const float b2v = b2[exp * H_DIM + col];
#pragma unroll
      for (int i = 0; i < 4; ++i) {
        if (toks[i] >= 0)
          atomicAdd(out + (size_t)toks[i] * H_DIM + col, ss[i] * (acc[fm][fn][i] + b2v));
      }
    }
  }
}

// standalone w2 transpose for the (ws too small) sequential path
__global__ __launch_bounds__(256) void tcvt2_k(const float* __restrict__ in,
                                               unsigned short* __restrict__ out) {
  fast_tcvt(in, out, F_DIM, H_DIM, blockIdx.x);
}

extern "C" void kernel_launch(void* const* d_in, const int* in_sizes, int n_in,
                              void* d_out, int out_size, void* d_ws, size_t ws_size,
                              hipStream_t stream) {
  const float* x  = (const float*)d_in[0];
  const float* rw = (const float*)d_in[1];
  const float* w1 = (const float*)d_in[2];
  const float* b1 = (const float*)d_in[3];
  const float* w2 = (const float*)d_in[4];
  const float* b2 = (const float*)d_in[5];
  float* out = (float*)d_out;
  char* ws = (char*)d_ws;

  int*   meta       = (int*)ws;
  int*   topk_e     = (int*)(ws + 4096);
  float* topk_s     = (float*)(ws + 20480);
  int*   slot_token = (int*)(ws + 36864);
  float* slot_score = (float*)(ws + 57344);
  unsigned short* xb   = (unsigned short*)(ws + (1ull << 20));
  unsigned short* hbuf = (unsigned short*)(ws + (6ull << 20));
  unsigned short* wt1  = (unsigned short*)(ws + (48ull << 20));
  const size_t W = (size_t)E_NUM * H_DIM * F_DIM * 2;   // 64 MiB
  unsigned short* wt2  = (unsigned short*)(ws + (48ull << 20) + W);
  const size_t NEED_FULL = (48ull << 20) + 2 * W;       // 176 MiB
  const bool full = ws_size >= NEED_FULL;

  hipMemsetAsync(meta, 0, 256, stream);
  hipMemsetAsync(slot_token, 0xFF, MAX_SLOTS * sizeof(int), stream);  // -1 fill
  hipMemsetAsync(out, 0, (size_t)N_TOK * H_DIM * sizeof(float), stream);

  // w1-transpose | x-convert | router, one launch
  prep1_k<<<TCVT_BLKS + 1024 + 512, 256, 0, stream>>>(w1, wt1, x, xb, rw, meta, topk_e, topk_s);
  scatter_k<<<1, 256, 0, stream>>>(meta, topk_e, topk_s, slot_token, slot_score);

  if (full) {
    gemm1_f<<<G1_GRID + TCVT_BLKS, 256, 0, stream>>>(xb, wt1, b1, meta, slot_token, hbuf, w2, wt2);
    gemm2_f<<<G2_GRID, 256, 0, stream>>>(hbuf, wt2, b2, meta, slot_token, slot_score, out);
  } else {
    gemm1_f<<<G1_GRID, 256, 0, stream>>>(xb, wt1, b1, meta, slot_token, hbuf, w2, wt1);
    tcvt2_k<<<TCVT_BLKS, 256, 0, stream>>>(w2, wt1);   // reuse wt1 after gemm1 consumed it
    gemm2_f<<<G2_GRID, 256, 0, stream>>>(hbuf, wt1, b2, meta, slot_token, slot_score, out);
  }
}